// Round 1
// 578.526 us; speedup vs baseline: 1.0451x; 1.0451x over previous
//
#include <hip/hip_runtime.h>

// Problem constants (from reference)
#define NUu 200000
#define NIi 100000
#define EE  600000
// D = H = 128

#define SCAP 1024   // LDS src-index window capacity (block edge windows are ~192/~384 avg)
#define NB_USER 3125   // (NUu+63)/64
#define NB_ITEM 1563   // (NIi+63)/64

typedef short short8 __attribute__((ext_vector_type(8)));
typedef float floatx4 __attribute__((ext_vector_type(4)));

// float -> bf16 bits, round-to-nearest-even
__device__ __forceinline__ unsigned short f2bf(float f) {
  union { float f; unsigned int u; } v; v.f = f;
  unsigned int r = v.u + 0x7FFFu + ((v.u >> 16) & 1u);
  return (unsigned short)(r >> 16);
}

// ---------------------------------------------------------------------------
// K0a: fused weights  W1 = Wl @ W2nd,  W2 = Wr @ W2nd  -> bf16, packed in the
// MFMA B-fragment layout:  elem index = ((n_tile*8 + k_step)*64 + quad*16 + n_lo)*8 + j
// where k_global = k_step*32 + quad*8 + j, n = n_tile*16 + n_lo.
// ---------------------------------------------------------------------------
__global__ __launch_bounds__(128) void fuse_weights(
    const float* __restrict__ Wl_iu, const float* __restrict__ Wr_iu,
    const float* __restrict__ Wl_ui, const float* __restrict__ Wr_ui,
    const float* __restrict__ W_user, const float* __restrict__ W_item,
    unsigned short* __restrict__ Wp_user, unsigned short* __restrict__ Wp_item)
{
  int d = blockIdx.x;        // 0..127 (row of first factor)
  int m = blockIdx.y;        // which matrix
  int h = threadIdx.x;       // 0..127 (output col)
  const float* A; const float* W; unsigned short* dst; int koff;
  switch (m) {
    case 0:  A = Wl_iu; W = W_user; dst = Wp_user; koff = 0;   break;
    case 1:  A = Wr_iu; W = W_user; dst = Wp_user; koff = 128; break;
    case 2:  A = Wl_ui; W = W_item; dst = Wp_item; koff = 0;   break;
    default: A = Wr_ui; W = W_item; dst = Wp_item; koff = 128; break;
  }
  float acc = 0.f;
  for (int k = 0; k < 128; ++k) acc += A[d * 128 + k] * W[k * 128 + h];
  int kg = koff + d;
  int ks = kg >> 5, quad = (kg >> 3) & 3, j = kg & 7;
  int nt = h >> 4, nlo = h & 15;
  int idx = ((nt * 8 + ks) * 64 + quad * 16 + nlo) * 8 + j;
  dst[idx] = f2bf(acc);
}

// K0b: fused bias = bl @ W2nd + b2nd   (fp32). grid 2, block 128.
__global__ __launch_bounds__(128) void fuse_bias(
    const float* __restrict__ bl_iu, const float* __restrict__ b_user, const float* __restrict__ Wu,
    const float* __restrict__ bl_ui, const float* __restrict__ b_item, const float* __restrict__ Wi,
    float* __restrict__ bias_user, float* __restrict__ bias_item)
{
  int h = threadIdx.x;
  const float* bl = blockIdx.x ? bl_ui : bl_iu;
  const float* b2 = blockIdx.x ? b_item : b_user;
  const float* W  = blockIdx.x ? Wi : Wu;
  float* o        = blockIdx.x ? bias_item : bias_user;
  float acc = b2[h];
  for (int k = 0; k < 128; ++k) acc += bl[k] * W[k * 128 + h];
  o[h] = acc;
}

// ---------------------------------------------------------------------------
// CSR construction: hist -> scan1 -> scan2 -> scan3 -> fill
// (user/item pairs merged into single launches via blockIdx.y / blockIdx.x)
// ---------------------------------------------------------------------------
__global__ __launch_bounds__(256) void hist2(
    const int* __restrict__ edst_iu, int* __restrict__ cnt_user,
    const int* __restrict__ edst_ui, int* __restrict__ cnt_item)
{
  int e = blockIdx.x * 256 + threadIdx.x;
  if (e >= EE) return;
  const int* edst = blockIdx.y ? edst_ui : edst_iu;
  int* cnt        = blockIdx.y ? cnt_item : cnt_user;
  atomicAdd(&cnt[edst[e]], 1);
}

__global__ __launch_bounds__(256) void scan1(
    const int* __restrict__ cnt_u, int* __restrict__ blk_u,
    const int* __restrict__ cnt_i, int* __restrict__ blk_i)
{
  __shared__ int s[256];
  int b = blockIdx.x, t = threadIdx.x;
  const int* cnt; int* blksum; int N;
  if (blockIdx.y == 0) { cnt = cnt_u; blksum = blk_u; N = NUu; }
  else { if (b >= 98) return; cnt = cnt_i; blksum = blk_i; N = NIi; }
  int base = b * 1024 + t * 4;
  int v = 0;
  #pragma unroll
  for (int j = 0; j < 4; ++j) { int i = base + j; if (i < N) v += cnt[i]; }
  s[t] = v; __syncthreads();
  for (int off = 128; off > 0; off >>= 1) {
    if (t < off) s[t] += s[t + off];
    __syncthreads();
  }
  if (t == 0) blksum[b] = s[0];
}

__global__ __launch_bounds__(256) void scan2(
    const int* __restrict__ bs_u, int* __restrict__ bo_u,
    const int* __restrict__ bs_i, int* __restrict__ bo_i)
{
  __shared__ int s[256];
  int t = threadIdx.x;
  const int* blksum = blockIdx.x ? bs_i : bs_u;
  int* blkoff       = blockIdx.x ? bo_i : bo_u;
  int nblk          = blockIdx.x ? 98 : 196;
  int v = t < nblk ? blksum[t] : 0;
  s[t] = v; __syncthreads();
  for (int off = 1; off < 256; off <<= 1) {
    int tmp = t >= off ? s[t - off] : 0;
    __syncthreads();
    s[t] += tmp;
    __syncthreads();
  }
  if (t < nblk) blkoff[t] = s[t] - v;
}

__global__ __launch_bounds__(256) void scan3(
    const int* __restrict__ cnt_u, const int* __restrict__ bo_u,
    int* __restrict__ row_u, int* __restrict__ fil_u,
    const int* __restrict__ cnt_i, const int* __restrict__ bo_i,
    int* __restrict__ row_i, int* __restrict__ fil_i)
{
  __shared__ int s[256];
  int b = blockIdx.x, t = threadIdx.x;
  const int* cnt; const int* blkoff; int* rowp; int* fillp; int N;
  if (blockIdx.y == 0) { cnt = cnt_u; blkoff = bo_u; rowp = row_u; fillp = fil_u; N = NUu; }
  else { if (b >= 98) return; cnt = cnt_i; blkoff = bo_i; rowp = row_i; fillp = fil_i; N = NIi; }
  int base = b * 1024 + t * 4;
  int v[4]; int sum = 0;
  #pragma unroll
  for (int j = 0; j < 4; ++j) { int i = base + j; v[j] = (i < N) ? cnt[i] : 0; sum += v[j]; }
  s[t] = sum; __syncthreads();
  for (int off = 1; off < 256; off <<= 1) {
    int tmp = t >= off ? s[t - off] : 0;
    __syncthreads();
    s[t] += tmp;
    __syncthreads();
  }
  int ex = s[t] - sum + blkoff[b];
  #pragma unroll
  for (int j = 0; j < 4; ++j) {
    int i = base + j;
    if (i < N) { rowp[i] = ex; fillp[i] = ex; ex += v[j]; }
  }
}

__global__ __launch_bounds__(256) void fill2(
    const int* __restrict__ esrc_iu, const int* __restrict__ edst_iu,
    int* __restrict__ fill_user, int* __restrict__ srcs_user,
    const int* __restrict__ esrc_ui, const int* __restrict__ edst_ui,
    int* __restrict__ fill_item, int* __restrict__ srcs_item)
{
  int e = blockIdx.x * 256 + threadIdx.x;
  if (e >= EE) return;
  const int* esrc; const int* edst; int* fillp; int* srcs;
  if (blockIdx.y == 0) { esrc = esrc_iu; edst = edst_iu; fillp = fill_user; srcs = srcs_user; }
  else                 { esrc = esrc_ui; edst = edst_ui; fillp = fill_item; srcs = srcs_item; }
  int d = edst[e];
  int p = atomicAdd(&fillp[d], 1);
  srcs[p] = esrc[e];
}

// ---------------------------------------------------------------------------
// K3 v2: fused node kernel, latency-bound fixes:
//  (1) K-split LDS staging: 16 KB A buffer reused for own-half (K=128..255)
//      then agg-half (K=0..127). LDS/block 37.4 KB -> ~20.7 KB => 6-7 blocks/CU
//      (occupancy 38% -> ~70%), which is the main latency-hiding lever.
//  (2) Parity-split gather: ALL 32 lanes of a node work the deg loop (even/odd
//      edges), combined with __shfl_xor(.,16) -> half the serial trips.
//  (3) XOR bank swizzle on A slots (mlo ^ (slice&7)): pack writes were 16-32way
//      bank conflicts (5.6M cycles/dispatch); now conflict-free. Read side uses
//      the same XOR; bank-class balance preserved.
//  (4) user+item grids merged into one launch.
// mfma_f32_16x16x32_bf16 C/D: col=lane&15, row=(lane>>4)*4+reg   (m89/m91)
// ---------------------------------------------------------------------------
__global__ __launch_bounds__(256, 6) void fused_gemm(
    const float* __restrict__ xu_own, const float* __restrict__ xu_src,
    const int* __restrict__ rowp_u, const int* __restrict__ srcs_u,
    const unsigned short* __restrict__ Wp_u, const float* __restrict__ bias_u,
    const float* __restrict__ xi_own, const float* __restrict__ xi_src,
    const int* __restrict__ rowp_i, const int* __restrict__ srcs_i,
    const unsigned short* __restrict__ Wp_i, const float* __restrict__ bias_i,
    float* __restrict__ out)
{
  __shared__ __align__(16) uint4 ldsA4[1024];    // 16 KB packed A (half of K)
  __shared__ int ldsS[SCAP];                     // 4 KB src-index window
  __shared__ int rb[65];                         // block row pointers
  int t = threadIdx.x;
  int b = blockIdx.x;

  const float* xown; const float* xsrc; const int* rowp; const int* srcs;
  const unsigned short* Wp; const float* bias; float* outbase; int nvalid; int node0;
  if (b < NB_USER) {
    xown = xu_own; xsrc = xu_src; rowp = rowp_u; srcs = srcs_u;
    Wp = Wp_u; bias = bias_u; outbase = out; nvalid = NUu; node0 = b * 64;
  } else {
    xown = xi_own; xsrc = xi_src; rowp = rowp_i; srcs = srcs_i;
    Wp = Wp_i; bias = bias_i; outbase = out + (size_t)NUu * 128;
    nvalid = NIi; node0 = (b - NB_USER) * 64;
  }

  // ---- phase 0: row pointers ----
  if (t < 65) {
    int node = node0 + t;
    rb[t] = node < nvalid ? rowp[node] : EE;
  }
  __syncthreads();
  int rs0 = rb[0];
  int W = rb[64] - rs0;                          // block edge count
  for (int idx = t; idx < W && idx < SCAP; idx += 256)
    ldsS[idx] = srcs[rs0 + idx];

  // ---- phase 1: own-half (K=128..255) bf16-pack into swizzled A slots ----
  #pragma unroll
  for (int i = 0; i < 4; ++i) {
    int oid = t + i * 256;                       // 0..1023
    int m = oid >> 4;                            // node within block
    int oct = oid & 15;                          // 8-float k-slice (own-local)
    int node = node0 + m;
    uint4 p; p.x = 0u; p.y = 0u; p.z = 0u; p.w = 0u;
    if (node < nvalid) {
      const float4* p4 = (const float4*)(xown + (size_t)node * 128 + oct * 8);
      float4 lo = p4[0], hi = p4[1];
      p.x = (unsigned)f2bf(lo.x) | ((unsigned)f2bf(lo.y) << 16);
      p.y = (unsigned)f2bf(lo.z) | ((unsigned)f2bf(lo.w) << 16);
      p.z = (unsigned)f2bf(hi.x) | ((unsigned)f2bf(hi.y) << 16);
      p.w = (unsigned)f2bf(hi.z) | ((unsigned)f2bf(hi.w) << 16);
    }
    int ks = oct >> 2, quad = oct & 3;
    int mt = m >> 4, mlo = m & 15;
    ldsA4[(mt * 4 + ks) * 64 + quad * 16 + (mlo ^ (oct & 7))] = p;
  }
  __syncthreads();

  // ---- phase 2: MFMA own half (k_global 128..255) ----
  int wave = t >> 6, lane = t & 63;
  int quadr = lane >> 4, mlor = lane & 15;
  floatx4 acc[8];
  #pragma unroll
  for (int i = 0; i < 8; ++i) acc[i] = (floatx4){0.f, 0.f, 0.f, 0.f};
  const short8* A = (const short8*)ldsA4;
  const short8* B = (const short8*)Wp;
  #pragma unroll
  for (int kk = 0; kk < 4; ++kk) {
    short8 af = A[(wave * 4 + kk) * 64 + quadr * 16 + (mlor ^ ((kk * 4 + quadr) & 7))];
    #pragma unroll
    for (int nt = 0; nt < 8; ++nt) {
      short8 bf = B[(nt * 8 + 4 + kk) * 64 + lane];
      acc[nt] = __builtin_amdgcn_mfma_f32_16x16x32_bf16(af, bf, acc[nt], 0, 0, 0);
    }
  }
  __syncthreads();                               // ldsA consumed, safe to refill

  // ---- phase 3: gather+mean with parity-split (all 32 lanes per node) ----
  #pragma unroll
  for (int i = 0; i < 8; ++i) {
    int oid = t + i * 256;                       // 0..2047
    int m = oid >> 5;                            // node within block (0..63)
    int oct = oid & 31;
    int slice = oct & 15;                        // 8-float k-slice
    int par = oct >> 4;                          // edge parity this lane owns
    int node = node0 + m;
    float a0=0,a1=0,a2=0,a3=0,a4=0,a5=0,a6=0,a7=0;
    int deg = 0;
    if (node < nvalid) {
      int erel = rb[m] - rs0;
      deg = rb[m + 1] - rb[m];
      int k0 = slice * 8;
      int e = par;
      for (; e + 2 < deg; e += 4) {              // 2 edges (stride 2) per trip
        int q0 = erel + e, q1 = q0 + 2;
        int s0 = (q0 < SCAP) ? ldsS[q0] : srcs[rs0 + q0];
        int s1 = (q1 < SCAP) ? ldsS[q1] : srcs[rs0 + q1];
        const float4* r0 = (const float4*)(xsrc + (size_t)s0 * 128 + k0);
        const float4* r1 = (const float4*)(xsrc + (size_t)s1 * 128 + k0);
        float4 l0 = r0[0], h0 = r0[1];
        float4 l1 = r1[0], h1 = r1[1];
        a0 += l0.x + l1.x; a1 += l0.y + l1.y;
        a2 += l0.z + l1.z; a3 += l0.w + l1.w;
        a4 += h0.x + h1.x; a5 += h0.y + h1.y;
        a6 += h0.z + h1.z; a7 += h0.w + h1.w;
      }
      if (e < deg) {
        int q = erel + e;
        int s = (q < SCAP) ? ldsS[q] : srcs[rs0 + q];
        const float4* r = (const float4*)(xsrc + (size_t)s * 128 + k0);
        float4 l = r[0], h = r[1];
        a0 += l.x; a1 += l.y; a2 += l.z; a3 += l.w;
        a4 += h.x; a5 += h.y; a6 += h.z; a7 += h.w;
      }
    }
    // combine even/odd partial sums (partner lane is same node, same wave)
    a0 += __shfl_xor(a0, 16); a1 += __shfl_xor(a1, 16);
    a2 += __shfl_xor(a2, 16); a3 += __shfl_xor(a3, 16);
    a4 += __shfl_xor(a4, 16); a5 += __shfl_xor(a5, 16);
    a6 += __shfl_xor(a6, 16); a7 += __shfl_xor(a7, 16);
    if (par == 0) {
      float sc = deg > 0 ? 1.0f / (float)deg : 0.f;
      uint4 p;
      p.x = (unsigned)f2bf(a0 * sc) | ((unsigned)f2bf(a1 * sc) << 16);
      p.y = (unsigned)f2bf(a2 * sc) | ((unsigned)f2bf(a3 * sc) << 16);
      p.z = (unsigned)f2bf(a4 * sc) | ((unsigned)f2bf(a5 * sc) << 16);
      p.w = (unsigned)f2bf(a6 * sc) | ((unsigned)f2bf(a7 * sc) << 16);
      int ks = slice >> 2, quad = slice & 3;
      int mt = m >> 4, mlo = m & 15;
      ldsA4[(mt * 4 + ks) * 64 + quad * 16 + (mlo ^ (slice & 7))] = p;
    }
  }
  __syncthreads();

  // ---- phase 4: MFMA agg half (k_global 0..127) ----
  #pragma unroll
  for (int kk = 0; kk < 4; ++kk) {
    short8 af = A[(wave * 4 + kk) * 64 + quadr * 16 + (mlor ^ ((kk * 4 + quadr) & 7))];
    #pragma unroll
    for (int nt = 0; nt < 8; ++nt) {
      short8 bf = B[(nt * 8 + kk) * 64 + lane];
      acc[nt] = __builtin_amdgcn_mfma_f32_16x16x32_bf16(af, bf, acc[nt], 0, 0, 0);
    }
  }

  // ---- epilogue: bias + relu ----
  int col = lane & 15, qrow = (lane >> 4) * 4;
  #pragma unroll
  for (int nt = 0; nt < 8; ++nt) {
    int n = nt * 16 + col;
    float bv = bias[n];
    #pragma unroll
    for (int r2 = 0; r2 < 4; ++r2) {
      int node = node0 + wave * 16 + qrow + r2;
      if (node < nvalid) {
        float v = acc[nt][r2] + bv;
        outbase[(size_t)node * 128 + n] = v > 0.f ? v : 0.f;
      }
    }
  }
}

// ---------------------------------------------------------------------------
// Workspace layout (bytes), total ~8.54 MB (cnt_* zeroed each call):
//   cnt_user @0 800000 | cnt_item @800000 400000 | row_user @1200000 800000
//   row_item @2000000 400000 | fill_user @2400000 800000 | fill_item @3200000 400000
//   srcs_user @3600000 2400000 | srcs_item @6000000 2400000
//   blks_user @8400000 1024 | blks_item @8401024 1024
//   boff_user @8402048 1024 | boff_item @8403072 1024
//   Wp_user @8404224 65536 | Wp_item @8469760 65536
//   bias_user @8535296 512 | bias_item @8535808 512
// ---------------------------------------------------------------------------
extern "C" void kernel_launch(void* const* d_in, const int* in_sizes, int n_in,
                              void* d_out, int out_size, void* d_ws, size_t ws_size,
                              hipStream_t stream)
{
  const float* x_user = (const float*)d_in[0];
  const float* x_item = (const float*)d_in[1];
  const int* esrc_ui  = (const int*)d_in[2];
  const int* edst_ui  = (const int*)d_in[3];
  const int* esrc_iu  = (const int*)d_in[4];
  const int* edst_iu  = (const int*)d_in[5];
  const float* Wl_ui  = (const float*)d_in[6];
  const float* bl_ui  = (const float*)d_in[7];
  const float* Wr_ui  = (const float*)d_in[8];
  const float* Wl_iu  = (const float*)d_in[9];
  const float* bl_iu  = (const float*)d_in[10];
  const float* Wr_iu  = (const float*)d_in[11];
  const float* W_user = (const float*)d_in[12];
  const float* b_user = (const float*)d_in[13];
  const float* W_item = (const float*)d_in[14];
  const float* b_item = (const float*)d_in[15];
  float* out = (float*)d_out;

  char* ws = (char*)d_ws;
  int* cnt_user  = (int*)(ws + 0);
  int* cnt_item  = (int*)(ws + 800000);
  int* row_user  = (int*)(ws + 1200000);
  int* row_item  = (int*)(ws + 2000000);
  int* fill_user = (int*)(ws + 2400000);
  int* fill_item = (int*)(ws + 3200000);
  int* srcs_user = (int*)(ws + 3600000);
  int* srcs_item = (int*)(ws + 6000000);
  int* blks_user = (int*)(ws + 8400000);
  int* blks_item = (int*)(ws + 8401024);
  int* boff_user = (int*)(ws + 8402048);
  int* boff_item = (int*)(ws + 8403072);
  unsigned short* Wp_user = (unsigned short*)(ws + 8404224);
  unsigned short* Wp_item = (unsigned short*)(ws + 8469760);
  float* bias_user = (float*)(ws + 8535296);
  float* bias_item = (float*)(ws + 8535808);

  // zero only the histograms (1.2 MB)
  hipMemsetAsync(d_ws, 0, 1200000, stream);

  fuse_weights<<<dim3(128, 4), 128, 0, stream>>>(Wl_iu, Wr_iu, Wl_ui, Wr_ui,
                                                 W_user, W_item, Wp_user, Wp_item);
  fuse_bias<<<2, 128, 0, stream>>>(bl_iu, b_user, W_user, bl_ui, b_item, W_item,
                                   bias_user, bias_item);

  const int EB = (EE + 255) / 256;            // 2344
  const int NBU = (NUu + 1023) / 1024;        // 196

  hist2<<<dim3(EB, 2), 256, 0, stream>>>(edst_iu, cnt_user, edst_ui, cnt_item);
  scan1<<<dim3(NBU, 2), 256, 0, stream>>>(cnt_user, blks_user, cnt_item, blks_item);
  scan2<<<2, 256, 0, stream>>>(blks_user, boff_user, blks_item, boff_item);
  scan3<<<dim3(NBU, 2), 256, 0, stream>>>(cnt_user, boff_user, row_user, fill_user,
                                          cnt_item, boff_item, row_item, fill_item);
  fill2<<<dim3(EB, 2), 256, 0, stream>>>(esrc_iu, edst_iu, fill_user, srcs_user,
                                         esrc_ui, edst_ui, fill_item, srcs_item);

  fused_gemm<<<NB_USER + NB_ITEM, 256, 0, stream>>>(
      x_user, x_item, row_user, srcs_user, Wp_user, bias_user,
      x_item, x_user, row_item, srcs_item, Wp_item, bias_item, out);
}

// Round 2
// 567.519 us; speedup vs baseline: 1.0653x; 1.0194x over previous
//
#include <hip/hip_runtime.h>

// Problem constants (from reference)
#define NUu 200000
#define NIi 100000
#define EE  600000
// D = H = 128

#define SCAP 768      // LDS src-index window (block windows avg 192/384, Poisson sd ~14/20 -> 768 never hit in practice; global fallback covers)
#define NB_USER 3125  // (NUu+63)/64
#define NB_ITEM 1563  // (NIi+63)/64

// prep kernel grid sections
#define PB_HIST   586         // 586*1024 >= EE
#define PB_W0     1172        // hist user + hist item
#define PB_B0     1428        // + 256 fuse_weights blocks
#define PB_CU0    1429        // + 1 fuse_bias block
#define PB_CI0    13929       // + 12500 conv-user blocks (200000*128/2048)
#define PB_END    20179       // + 6250 conv-item blocks (100000*128/2048)

typedef short short8 __attribute__((ext_vector_type(8)));
typedef float floatx4 __attribute__((ext_vector_type(4)));

// float -> bf16 bits, round-to-nearest-even
__device__ __forceinline__ unsigned short f2bf(float f) {
  union { float f; unsigned int u; } v; v.f = f;
  unsigned int r = v.u + 0x7FFFu + ((v.u >> 16) & 1u);
  return (unsigned short)(r >> 16);
}
// bf16 pair (packed in u32) -> f32
__device__ __forceinline__ float bflo(unsigned int u) { return __uint_as_float(u << 16); }
__device__ __forceinline__ float bfhi(unsigned int u) { return __uint_as_float(u & 0xFFFF0000u); }

// ---------------------------------------------------------------------------
// prep: ONE launch fusing 4 independent jobs so the latency-bound random-atomic
// histogram blocks overlap with streaming conversion / weight-fusion blocks:
//   [0,586)        hist user  (edst_iu -> cnt_user), int4 edge loads
//   [586,1172)     hist item  (edst_ui -> cnt_item)
//   [1172,1428)    fused weights W1=Wl@W2, W2=Wr@W2 -> bf16 MFMA B-frag layout
//                  elem = ((nt*8+ks)*64 + quad*16 + nlo)*8 + j,
//                  k = ks*32+quad*8+j, n = nt*16+nlo
//   {1428}         fused bias  bl@W2 + b2
//   [1429,13929)   x_user -> bf16 (halves gather row size; 77MB bf16 is L3-resident)
//   [13929,20179)  x_item -> bf16
// Fallback (ws too small for bf16 arrays): launch only [0,1429).
// ---------------------------------------------------------------------------
__global__ __launch_bounds__(256) void prep(
    const int* __restrict__ edst_iu, int* __restrict__ cnt_user,
    const int* __restrict__ edst_ui, int* __restrict__ cnt_item,
    const float* __restrict__ Wl_iu, const float* __restrict__ Wr_iu,
    const float* __restrict__ Wl_ui, const float* __restrict__ Wr_ui,
    const float* __restrict__ W_user, const float* __restrict__ W_item,
    unsigned short* __restrict__ Wp_user, unsigned short* __restrict__ Wp_item,
    const float* __restrict__ bl_iu, const float* __restrict__ b_user,
    const float* __restrict__ bl_ui, const float* __restrict__ b_item,
    float* __restrict__ bias_user, float* __restrict__ bias_item,
    const float* __restrict__ x_user, const float* __restrict__ x_item,
    unsigned short* __restrict__ xb_user, unsigned short* __restrict__ xb_item)
{
  int b = blockIdx.x, t = threadIdx.x;
  if (b < PB_W0) {
    // ---- histograms ----
    const int* edst = b < PB_HIST ? edst_iu : edst_ui;
    int* cnt        = b < PB_HIST ? cnt_user : cnt_item;
    int local       = b < PB_HIST ? b : b - PB_HIST;
    int idx = local * 1024 + t * 4;
    if (idx < EE) {                       // EE%4==0 -> whole int4 valid
      int4 v = *(const int4*)(edst + idx);
      atomicAdd(&cnt[v.x], 1); atomicAdd(&cnt[v.y], 1);
      atomicAdd(&cnt[v.z], 1); atomicAdd(&cnt[v.w], 1);
    }
  } else if (b < PB_B0) {
    // ---- fused weights ----
    int flat = (b - PB_W0) * 256 + t;     // 0..65535
    int h = flat & 127, d = (flat >> 7) & 127, m = flat >> 14;
    const float* A; const float* W; unsigned short* dst; int koff;
    switch (m) {
      case 0:  A = Wl_iu; W = W_user; dst = Wp_user; koff = 0;   break;
      case 1:  A = Wr_iu; W = W_user; dst = Wp_user; koff = 128; break;
      case 2:  A = Wl_ui; W = W_item; dst = Wp_item; koff = 0;   break;
      default: A = Wr_ui; W = W_item; dst = Wp_item; koff = 128; break;
    }
    float acc = 0.f;
    for (int k = 0; k < 128; ++k) acc += A[d * 128 + k] * W[k * 128 + h];
    int kg = koff + d;
    int ks = kg >> 5, quad = (kg >> 3) & 3, j = kg & 7;
    int nt = h >> 4, nlo = h & 15;
    dst[((nt * 8 + ks) * 64 + quad * 16 + nlo) * 8 + j] = f2bf(acc);
  } else if (b == PB_B0) {
    // ---- fused bias ----
    int pair = t >> 7, h = t & 127;
    const float* bl = pair ? bl_ui : bl_iu;
    const float* b2 = pair ? b_item : b_user;
    const float* W  = pair ? W_item : W_user;
    float* o        = pair ? bias_item : bias_user;
    float acc = b2[h];
    for (int k = 0; k < 128; ++k) acc += bl[k] * W[k * 128 + h];
    o[h] = acc;
  } else {
    // ---- fp32 -> bf16 conversion (exact block coverage, no guards needed) ----
    const float* src; unsigned short* dst; long base;
    if (b < PB_CI0) { src = x_user; dst = xb_user; base = (long)(b - PB_CU0) * 2048 + t * 8; }
    else            { src = x_item; dst = xb_item; base = (long)(b - PB_CI0) * 2048 + t * 8; }
    const float4* p4 = (const float4*)(src + base);
    float4 lo = p4[0], hi = p4[1];
    uint4 p;
    p.x = (unsigned)f2bf(lo.x) | ((unsigned)f2bf(lo.y) << 16);
    p.y = (unsigned)f2bf(lo.z) | ((unsigned)f2bf(lo.w) << 16);
    p.z = (unsigned)f2bf(hi.x) | ((unsigned)f2bf(hi.y) << 16);
    p.w = (unsigned)f2bf(hi.z) | ((unsigned)f2bf(hi.w) << 16);
    *(uint4*)(dst + base) = p;
  }
}

// ---------------------------------------------------------------------------
// scan1: per-1024-chunk sums (user y=0 196 blocks, item y=1 98 blocks)
// ---------------------------------------------------------------------------
__global__ __launch_bounds__(256) void scan1(
    const int* __restrict__ cnt_u, int* __restrict__ blk_u,
    const int* __restrict__ cnt_i, int* __restrict__ blk_i)
{
  __shared__ int s[256];
  int b = blockIdx.x, t = threadIdx.x;
  const int* cnt; int* blksum; int N;
  if (blockIdx.y == 0) { cnt = cnt_u; blksum = blk_u; N = NUu; }
  else { if (b >= 98) return; cnt = cnt_i; blksum = blk_i; N = NIi; }
  int base = b * 1024 + t * 4;
  int v = 0;
  #pragma unroll
  for (int j = 0; j < 4; ++j) { int i = base + j; if (i < N) v += cnt[i]; }
  s[t] = v; __syncthreads();
  for (int off = 128; off > 0; off >>= 1) {
    if (t < off) s[t] += s[t + off];
    __syncthreads();
  }
  if (t == 0) blksum[b] = s[0];
}

// ---------------------------------------------------------------------------
// scan3: absorbs old scan2 — every block locally prefix-scans the block sums
// (<=196 values, 8 LDS steps) to get its own offset, then does the row scan.
// ---------------------------------------------------------------------------
__global__ __launch_bounds__(256) void scan3(
    const int* __restrict__ cnt_u, const int* __restrict__ blks_u,
    int* __restrict__ row_u, int* __restrict__ fil_u,
    const int* __restrict__ cnt_i, const int* __restrict__ blks_i,
    int* __restrict__ row_i, int* __restrict__ fil_i)
{
  __shared__ int s[256];
  int b = blockIdx.x, t = threadIdx.x;
  const int* cnt; const int* blksum; int* rowp; int* fillp; int N; int nblk;
  if (blockIdx.y == 0) { cnt = cnt_u; blksum = blks_u; rowp = row_u; fillp = fil_u; N = NUu; nblk = 196; }
  else { if (b >= 98) return; cnt = cnt_i; blksum = blks_i; rowp = row_i; fillp = fil_i; N = NIi; nblk = 98; }

  // block offset = exclusive prefix of blksum at b
  int v2 = t < nblk ? blksum[t] : 0;
  s[t] = v2; __syncthreads();
  for (int off = 1; off < 256; off <<= 1) {
    int tmp = t >= off ? s[t - off] : 0;
    __syncthreads();
    s[t] += tmp;
    __syncthreads();
  }
  int blkoffb = (b == 0) ? 0 : s[b - 1];
  __syncthreads();

  int base = b * 1024 + t * 4;
  int v[4]; int sum = 0;
  #pragma unroll
  for (int j = 0; j < 4; ++j) { int i = base + j; v[j] = (i < N) ? cnt[i] : 0; sum += v[j]; }
  s[t] = sum; __syncthreads();
  for (int off = 1; off < 256; off <<= 1) {
    int tmp = t >= off ? s[t - off] : 0;
    __syncthreads();
    s[t] += tmp;
    __syncthreads();
  }
  int ex = s[t] - sum + blkoffb;
  #pragma unroll
  for (int j = 0; j < 4; ++j) {
    int i = base + j;
    if (i < N) { rowp[i] = ex; fillp[i] = ex; ex += v[j]; }
  }
}

__global__ __launch_bounds__(256) void fill2(
    const int* __restrict__ esrc_iu, const int* __restrict__ edst_iu,
    int* __restrict__ fill_user, int* __restrict__ srcs_user,
    const int* __restrict__ esrc_ui, const int* __restrict__ edst_ui,
    int* __restrict__ fill_item, int* __restrict__ srcs_item)
{
  int e = blockIdx.x * 256 + threadIdx.x;
  if (e >= EE) return;
  const int* esrc; const int* edst; int* fillp; int* srcs;
  if (blockIdx.y == 0) { esrc = esrc_iu; edst = edst_iu; fillp = fill_user; srcs = srcs_user; }
  else                 { esrc = esrc_ui; edst = edst_ui; fillp = fill_item; srcs = srcs_item; }
  int d = edst[e];
  int p = atomicAdd(&fillp[d], 1);
  srcs[p] = esrc[e];
}

// ---------------------------------------------------------------------------
// K3 v3: fused node kernel.
//  BF=true: x arrays pre-converted to bf16 -> gather rows 256B (half traffic),
//  77MB working set is L3-resident, own-half pack is a raw 16B copy.
//  Output stores nontemporal (out is never re-read; protects bf16 L3 residency).
//  SCAP 768 + launch_bounds(256,8): LDS 19.7KB -> 8 blocks/CU, VGPR capped 64.
// mfma_f32_16x16x32_bf16 C/D: col=lane&15, row=(lane>>4)*4+reg   (m89/m91)
// ---------------------------------------------------------------------------
template<bool BF>
__global__ __launch_bounds__(256, 8) void fused_gemm(
    const void* __restrict__ xu_own, const void* __restrict__ xu_src,
    const int* __restrict__ rowp_u, const int* __restrict__ srcs_u,
    const unsigned short* __restrict__ Wp_u, const float* __restrict__ bias_u,
    const void* __restrict__ xi_own, const void* __restrict__ xi_src,
    const int* __restrict__ rowp_i, const int* __restrict__ srcs_i,
    const unsigned short* __restrict__ Wp_i, const float* __restrict__ bias_i,
    float* __restrict__ out)
{
  __shared__ __align__(16) uint4 ldsA4[1024];    // 16 KB packed A (half of K)
  __shared__ int ldsS[SCAP];                     // 3 KB src-index window
  __shared__ int rb[65];
  int t = threadIdx.x;
  int b = blockIdx.x;

  const void* xown; const void* xsrc; const int* rowp; const int* srcs;
  const unsigned short* Wp; const float* bias; float* outbase; int nvalid; int node0;
  if (b < NB_USER) {
    xown = xu_own; xsrc = xu_src; rowp = rowp_u; srcs = srcs_u;
    Wp = Wp_u; bias = bias_u; outbase = out; nvalid = NUu; node0 = b * 64;
  } else {
    xown = xi_own; xsrc = xi_src; rowp = rowp_i; srcs = srcs_i;
    Wp = Wp_i; bias = bias_i; outbase = out + (size_t)NUu * 128;
    nvalid = NIi; node0 = (b - NB_USER) * 64;
  }

  // ---- phase 0: row pointers + src-index window ----
  if (t < 65) {
    int node = node0 + t;
    rb[t] = node < nvalid ? rowp[node] : EE;
  }
  __syncthreads();
  int rs0 = rb[0];
  int W = rb[64] - rs0;
  for (int idx = t; idx < W && idx < SCAP; idx += 256)
    ldsS[idx] = srcs[rs0 + idx];

  // ---- phase 1: own-half (K=128..255) pack into swizzled A slots ----
  #pragma unroll
  for (int i = 0; i < 4; ++i) {
    int oid = t + i * 256;
    int m = oid >> 4;                            // node within block
    int oct = oid & 15;                          // 8-elem k-slice
    int node = node0 + m;
    uint4 p; p.x = 0u; p.y = 0u; p.z = 0u; p.w = 0u;
    if (node < nvalid) {
      if constexpr (BF) {
        p = *(const uint4*)((const unsigned short*)xown + (size_t)node * 128 + oct * 8);
      } else {
        const float4* p4 = (const float4*)((const float*)xown + (size_t)node * 128 + oct * 8);
        float4 lo = p4[0], hi = p4[1];
        p.x = (unsigned)f2bf(lo.x) | ((unsigned)f2bf(lo.y) << 16);
        p.y = (unsigned)f2bf(lo.z) | ((unsigned)f2bf(lo.w) << 16);
        p.z = (unsigned)f2bf(hi.x) | ((unsigned)f2bf(hi.y) << 16);
        p.w = (unsigned)f2bf(hi.z) | ((unsigned)f2bf(hi.w) << 16);
      }
    }
    int ks = oct >> 2, quad = oct & 3;
    int mt = m >> 4, mlo = m & 15;
    ldsA4[(mt * 4 + ks) * 64 + quad * 16 + (mlo ^ (oct & 7))] = p;
  }
  __syncthreads();

  // ---- phase 2: MFMA own half (k_global 128..255) ----
  int wave = t >> 6, lane = t & 63;
  int quadr = lane >> 4, mlor = lane & 15;
  floatx4 acc[8];
  #pragma unroll
  for (int i = 0; i < 8; ++i) acc[i] = (floatx4){0.f, 0.f, 0.f, 0.f};
  const short8* A = (const short8*)ldsA4;
  const short8* B = (const short8*)Wp;
  #pragma unroll
  for (int kk = 0; kk < 4; ++kk) {
    short8 af = A[(wave * 4 + kk) * 64 + quadr * 16 + (mlor ^ ((kk * 4 + quadr) & 7))];
    #pragma unroll
    for (int nt = 0; nt < 8; ++nt) {
      short8 bf = B[(nt * 8 + 4 + kk) * 64 + lane];
      acc[nt] = __builtin_amdgcn_mfma_f32_16x16x32_bf16(af, bf, acc[nt], 0, 0, 0);
    }
  }
  __syncthreads();                               // ldsA consumed, safe to refill

  // ---- phase 3: gather+mean, parity-split (all 32 lanes per node) ----
  #pragma unroll
  for (int i = 0; i < 8; ++i) {
    int oid = t + i * 256;
    int m = oid >> 5;
    int oct = oid & 31;
    int slice = oct & 15;
    int par = oct >> 4;
    int node = node0 + m;
    float a0=0,a1=0,a2=0,a3=0,a4=0,a5=0,a6=0,a7=0;
    int deg = 0;
    if (node < nvalid) {
      int erel = rb[m] - rs0;
      deg = rb[m + 1] - rb[m];
      int k0 = slice * 8;
      int e = par;
      if constexpr (BF) {
        const unsigned short* xs = (const unsigned short*)xsrc;
        for (; e + 2 < deg; e += 4) {
          int q0 = erel + e, q1 = q0 + 2;
          int s0 = (q0 < SCAP) ? ldsS[q0] : srcs[rs0 + q0];
          int s1 = (q1 < SCAP) ? ldsS[q1] : srcs[rs0 + q1];
          uint4 v0 = *(const uint4*)(xs + (size_t)s0 * 128 + k0);
          uint4 v1 = *(const uint4*)(xs + (size_t)s1 * 128 + k0);
          a0 += bflo(v0.x) + bflo(v1.x); a1 += bfhi(v0.x) + bfhi(v1.x);
          a2 += bflo(v0.y) + bflo(v1.y); a3 += bfhi(v0.y) + bfhi(v1.y);
          a4 += bflo(v0.z) + bflo(v1.z); a5 += bfhi(v0.z) + bfhi(v1.z);
          a6 += bflo(v0.w) + bflo(v1.w); a7 += bfhi(v0.w) + bfhi(v1.w);
        }
        if (e < deg) {
          int q = erel + e;
          int s = (q < SCAP) ? ldsS[q] : srcs[rs0 + q];
          uint4 v0 = *(const uint4*)(xs + (size_t)s * 128 + k0);
          a0 += bflo(v0.x); a1 += bfhi(v0.x);
          a2 += bflo(v0.y); a3 += bfhi(v0.y);
          a4 += bflo(v0.z); a5 += bfhi(v0.z);
          a6 += bflo(v0.w); a7 += bfhi(v0.w);
        }
      } else {
        const float* xs = (const float*)xsrc;
        for (; e + 2 < deg; e += 4) {
          int q0 = erel + e, q1 = q0 + 2;
          int s0 = (q0 < SCAP) ? ldsS[q0] : srcs[rs0 + q0];
          int s1 = (q1 < SCAP) ? ldsS[q1] : srcs[rs0 + q1];
          const float4* r0 = (const float4*)(xs + (size_t)s0 * 128 + k0);
          const float4* r1 = (const float4*)(xs + (size_t)s1 * 128 + k0);
          float4 l0 = r0[0], h0 = r0[1];
          float4 l1 = r1[0], h1 = r1[1];
          a0 += l0.x + l1.x; a1 += l0.y + l1.y;
          a2 += l0.z + l1.z; a3 += l0.w + l1.w;
          a4 += h0.x + h1.x; a5 += h0.y + h1.y;
          a6 += h0.z + h1.z; a7 += h0.w + h1.w;
        }
        if (e < deg) {
          int q = erel + e;
          int s = (q < SCAP) ? ldsS[q] : srcs[rs0 + q];
          const float4* r = (const float4*)(xs + (size_t)s * 128 + k0);
          float4 l = r[0], h = r[1];
          a0 += l.x; a1 += l.y; a2 += l.z; a3 += l.w;
          a4 += h.x; a5 += h.y; a6 += h.z; a7 += h.w;
        }
      }
    }
    a0 += __shfl_xor(a0, 16); a1 += __shfl_xor(a1, 16);
    a2 += __shfl_xor(a2, 16); a3 += __shfl_xor(a3, 16);
    a4 += __shfl_xor(a4, 16); a5 += __shfl_xor(a5, 16);
    a6 += __shfl_xor(a6, 16); a7 += __shfl_xor(a7, 16);
    if (par == 0) {
      float sc = deg > 0 ? 1.0f / (float)deg : 0.f;
      uint4 p;
      p.x = (unsigned)f2bf(a0 * sc) | ((unsigned)f2bf(a1 * sc) << 16);
      p.y = (unsigned)f2bf(a2 * sc) | ((unsigned)f2bf(a3 * sc) << 16);
      p.z = (unsigned)f2bf(a4 * sc) | ((unsigned)f2bf(a5 * sc) << 16);
      p.w = (unsigned)f2bf(a6 * sc) | ((unsigned)f2bf(a7 * sc) << 16);
      int ks = slice >> 2, quad = slice & 3;
      int mt = m >> 4, mlo = m & 15;
      ldsA4[(mt * 4 + ks) * 64 + quad * 16 + (mlo ^ (slice & 7))] = p;
    }
  }
  __syncthreads();

  // ---- phase 4: MFMA agg half (k_global 0..127) ----
  #pragma unroll
  for (int kk = 0; kk < 4; ++kk) {
    short8 af = A[(wave * 4 + kk) * 64 + quadr * 16 + (mlor ^ ((kk * 4 + quadr) & 7))];
    #pragma unroll
    for (int nt = 0; nt < 8; ++nt) {
      short8 bf = B[(nt * 8 + kk) * 64 + lane];
      acc[nt] = __builtin_amdgcn_mfma_f32_16x16x32_bf16(af, bf, acc[nt], 0, 0, 0);
    }
  }

  // ---- epilogue: bias + relu, nontemporal (out never re-read) ----
  int col = lane & 15, qrow = (lane >> 4) * 4;
  #pragma unroll
  for (int nt = 0; nt < 8; ++nt) {
    int n = nt * 16 + col;
    float bv = bias[n];
    #pragma unroll
    for (int r2 = 0; r2 < 4; ++r2) {
      int node = node0 + wave * 16 + qrow + r2;
      if (node < nvalid) {
        float v = acc[nt][r2] + bv;
        v = v > 0.f ? v : 0.f;
        __builtin_nontemporal_store(v, &outbase[(size_t)node * 128 + n]);
      }
    }
  }
}

// ---------------------------------------------------------------------------
// Workspace layout (bytes):
//   cnt_user @0 800000 | cnt_item @800000 400000 | row_user @1200000 800000
//   row_item @2000000 400000 | fill_user @2400000 800000 | fill_item @3200000 400000
//   srcs_user @3600000 2400000 | srcs_item @6000000 2400000
//   blks_user @8400000 1024 | blks_item @8401024 1024
//   (8402048..8404224 free) | Wp_user @8404224 65536 | Wp_item @8469760 65536
//   bias_user @8535296 512 | bias_item @8535808 512
//   xb_user @8536320 51200000 | xb_item @59736320 25600000 | end 85336320
// ---------------------------------------------------------------------------
extern "C" void kernel_launch(void* const* d_in, const int* in_sizes, int n_in,
                              void* d_out, int out_size, void* d_ws, size_t ws_size,
                              hipStream_t stream)
{
  const float* x_user = (const float*)d_in[0];
  const float* x_item = (const float*)d_in[1];
  const int* esrc_ui  = (const int*)d_in[2];
  const int* edst_ui  = (const int*)d_in[3];
  const int* esrc_iu  = (const int*)d_in[4];
  const int* edst_iu  = (const int*)d_in[5];
  const float* Wl_ui  = (const float*)d_in[6];
  const float* bl_ui  = (const float*)d_in[7];
  const float* Wr_ui  = (const float*)d_in[8];
  const float* Wl_iu  = (const float*)d_in[9];
  const float* bl_iu  = (const float*)d_in[10];
  const float* Wr_iu  = (const float*)d_in[11];
  const float* W_user = (const float*)d_in[12];
  const float* b_user = (const float*)d_in[13];
  const float* W_item = (const float*)d_in[14];
  const float* b_item = (const float*)d_in[15];
  float* out = (float*)d_out;

  char* ws = (char*)d_ws;
  int* cnt_user  = (int*)(ws + 0);
  int* cnt_item  = (int*)(ws + 800000);
  int* row_user  = (int*)(ws + 1200000);
  int* row_item  = (int*)(ws + 2000000);
  int* fill_user = (int*)(ws + 2400000);
  int* fill_item = (int*)(ws + 3200000);
  int* srcs_user = (int*)(ws + 3600000);
  int* srcs_item = (int*)(ws + 6000000);
  int* blks_user = (int*)(ws + 8400000);
  int* blks_item = (int*)(ws + 8401024);
  unsigned short* Wp_user = (unsigned short*)(ws + 8404224);
  unsigned short* Wp_item = (unsigned short*)(ws + 8469760);
  float* bias_user = (float*)(ws + 8535296);
  float* bias_item = (float*)(ws + 8535808);
  unsigned short* xb_user = (unsigned short*)(ws + 8536320);
  unsigned short* xb_item = (unsigned short*)(ws + 59736320UL);

  const bool bf = ws_size >= 85336320UL;

  // zero only the histograms (1.2 MB)
  hipMemsetAsync(d_ws, 0, 1200000, stream);

  prep<<<bf ? PB_END : PB_CU0, 256, 0, stream>>>(
      edst_iu, cnt_user, edst_ui, cnt_item,
      Wl_iu, Wr_iu, Wl_ui, Wr_ui, W_user, W_item, Wp_user, Wp_item,
      bl_iu, b_user, bl_ui, b_item, bias_user, bias_item,
      x_user, x_item, xb_user, xb_item);

  scan1<<<dim3(196, 2), 256, 0, stream>>>(cnt_user, blks_user, cnt_item, blks_item);
  scan3<<<dim3(196, 2), 256, 0, stream>>>(cnt_user, blks_user, row_user, fill_user,
                                          cnt_item, blks_item, row_item, fill_item);

  const int EB = (EE + 255) / 256;            // 2344
  fill2<<<dim3(EB, 2), 256, 0, stream>>>(esrc_iu, edst_iu, fill_user, srcs_user,
                                         esrc_ui, edst_ui, fill_item, srcs_item);

  if (bf) {
    fused_gemm<true><<<NB_USER + NB_ITEM, 256, 0, stream>>>(
        xb_user, xb_item, row_user, srcs_user, Wp_user, bias_user,
        xb_item, xb_user, row_item, srcs_item, Wp_item, bias_item, out);
  } else {
    fused_gemm<false><<<NB_USER + NB_ITEM, 256, 0, stream>>>(
        x_user, x_item, row_user, srcs_user, Wp_user, bias_user,
        x_item, x_user, row_item, srcs_item, Wp_item, bias_item, out);
  }
}